// Round 16
// baseline (163.170 us; speedup 1.0000x reference)
//
#include <hip/hip_runtime.h>

#define NN 20000
#define NE 640000
#define CH 128
#define NG 64
#define NSLICE (NN / 8)
#define CAP 96          // bin capacity; P(Poisson(32) > 96) ~ 1e-18

typedef unsigned short u16;
typedef unsigned char u8;
typedef __attribute__((ext_vector_type(8))) short short8;   // 8 bf16 (4 VGPRs)
typedef __attribute__((ext_vector_type(4))) float floatx4;  // 4 fp32 acc
typedef __attribute__((ext_vector_type(2))) float floatx2;

__device__ __forceinline__ u16 f2b(float f) {
    unsigned int u = __float_as_uint(f);
    u += 0x7fff + ((u >> 16) & 1);          // RNE
    return (u16)(u >> 16);
}
__device__ __forceinline__ u8 f2q(float f) {        // f32 -> fp8 e4m3 (OCP, HW cvt)
    return (u8)(__builtin_amdgcn_cvt_pk_fp8_f32(f, f, 0, false) & 0xff);
}
// accumulate 8 fp8 (uint2) into 4 float2 accs: 4 pk-cvt + 4 pk-add
__device__ __forceinline__ void acc8(uint2 q, floatx2* a) {
    a[0] += __builtin_amdgcn_cvt_pk_f32_fp8(q.x, false);
    a[1] += __builtin_amdgcn_cvt_pk_f32_fp8(q.x, true);
    a[2] += __builtin_amdgcn_cvt_pk_f32_fp8(q.y, false);
    a[3] += __builtin_amdgcn_cvt_pk_f32_fp8(q.y, true);
}
// one 16-edge round: 1 int4 index load + 4 row gathers
__device__ __forceinline__ void round16(const u8* __restrict__ in, const int* __restrict__ ssrc,
                                        int base, int slot, int boff, floatx2* a) {
    int4 si = *(const int4*)&ssrc[base + slot * 4];
    uint2 q0 = *(const uint2*)(in + (size_t)si.x * CH + boff);
    uint2 q1 = *(const uint2*)(in + (size_t)si.y * CH + boff);
    uint2 q2 = *(const uint2*)(in + (size_t)si.z * CH + boff);
    uint2 q3 = *(const uint2*)(in + (size_t)si.w * CH + boff);
    acc8(q0, a); acc8(q1, a); acc8(q2, a); acc8(q3, a);
}
__device__ __forceinline__ void tail16(const u8* __restrict__ in, const int* __restrict__ ssrc,
                                       int base, int e, int slot, int boff, floatx2* a) {
    int i0 = base + slot * 4;
    int4 si = *(const int4*)&ssrc[i0];
    bool ok0 = i0 + 0 < e, ok1 = i0 + 1 < e, ok2 = i0 + 2 < e, ok3 = i0 + 3 < e;
    int s0 = ok0 ? si.x : 0, s1 = ok1 ? si.y : 0, s2 = ok2 ? si.z : 0, s3 = ok3 ? si.w : 0;
    uint2 q0 = *(const uint2*)(in + (size_t)s0 * CH + boff);
    uint2 q1 = *(const uint2*)(in + (size_t)s1 * CH + boff);
    uint2 q2 = *(const uint2*)(in + (size_t)s2 * CH + boff);
    uint2 q3 = *(const uint2*)(in + (size_t)s3 * CH + boff);
    if (!ok0) q0 = make_uint2(0, 0);                   // fp8 0x00 == 0.0
    if (!ok1) q1 = make_uint2(0, 0);
    if (!ok2) q2 = make_uint2(0, 0);
    if (!ok3) q3 = make_uint2(0, 0);
    acc8(q0, a); acc8(q1, a); acc8(q2, a); acc8(q3, a);
}

// ---- prep: x->fp8, weights->bf16 B-frag order, zero gsum, binned CSR ------
__global__ __launch_bounds__(256) void prep(const float* __restrict__ x, u8* __restrict__ xq,
                                            const float* __restrict__ W1a, const float* __restrict__ W1b,
                                            const float* __restrict__ W2a, const float* __restrict__ W2b,
                                            u16* __restrict__ wt, float* __restrict__ gsum,
                                            const int* __restrict__ ei,
                                            int* __restrict__ cnt, int* __restrict__ ssrc) {
    int b = blockIdx.x;
    if (b < 2500) {                                   // x: 2.56M elems, 4/thread -> fp8
        int idx = (b * 256 + threadIdx.x) * 4;
        float4 v = *(const float4*)(x + idx);
        int pk = __builtin_amdgcn_cvt_pk_fp8_f32(v.x, v.y, 0, false);
        pk = __builtin_amdgcn_cvt_pk_fp8_f32(v.z, v.w, pk, true);
        *(unsigned int*)(xq + idx) = (unsigned int)pk;
    } else if (b < 2756) {                            // weights: 4 x 16384 elems (bf16 frags)
        int wi = b - 2500;                            // 0..255
        int m = wi >> 6;
        int r = (wi & 63) * 256 + threadIdx.x;        // 0..16383
        int j = r & 7, l16 = (r >> 3) & 15, quad = (r >> 7) & 3;
        int kc = (r >> 9) & 3, ct = (r >> 11) & 7;
        int n = ct * 16 + l16, k = kc * 32 + quad * 8 + j;
        const float* W = (m == 0) ? W1a : (m == 1) ? W1b : (m == 2) ? W2a : W2b;
        wt[m * 16384 + r] = f2b(W[k * 128 + n]);
    } else if (b < 2788) {                            // zero gsum (8192 floats)
        gsum[(b - 2756) * 256 + threadIdx.x] = 0.f;
    } else {                                          // binned CSR: 4096 blocks
        int idx = b - 2788;
        int slice = idx & 7, chunk = idx >> 3;        // 512 chunks x 1250 edges
        int lo = slice * NSLICE, hi = lo + NSLICE;
        int e0 = chunk * 1250, e1 = e0 + 1250;
        for (int e = e0 + threadIdx.x; e < e1; e += 256) {
            int dst = ei[NE + e];
            if (dst >= lo && dst < hi) {
                int pos = atomicAdd(&cnt[dst], 1);
                if (pos < CAP) ssrc[dst * CAP + pos] = ei[e];
            }
        }
    }
}

// ---- fused layer: aggregate (fp8 gather) + MLP, 16 nodes/block ------------
// Phase A: wave aggregates 4 nodes, INTERLEAVED IN PAIRS so 2 independent
// gather chains (8 rows + 2 index loads) are in flight per wave.
// Phase B: GEMM1/GEMM2, 8 col-tiles split 2/wave, H in LDS.
// DO_POOL: in-register masked reduce + global atomics to L2-resident gsum.
template <int DO_POOL>
__global__ __launch_bounds__(256) void layer(const u8* __restrict__ in,
                                             const int* __restrict__ cnt, const int* __restrict__ ssrc,
                                             const u16* __restrict__ wtA, const u16* __restrict__ wtB,
                                             const float* __restrict__ biasA, const float* __restrict__ biasB,
                                             u8* __restrict__ outq,
                                             const int* __restrict__ batch, float* __restrict__ gsum) {
    __shared__ u16 A[16 * 136];
    __shared__ u16 H[16 * 136];
    int t = threadIdx.x, wave = t >> 6, lane = t & 63;
    int quad = lane >> 4, l16 = lane & 15;
    int nb = blockIdx.x * 16;                          // 1250*16 = 20000 exact

    int gg[4], glo = 0, ghi = 0;
    if (DO_POOL) {
        glo = batch[nb]; ghi = batch[nb + 15];
        #pragma unroll
        for (int r = 0; r < 4; ++r)
            gg[r] = batch[nb + quad * 4 + r];
    }

    // ---- phase A: aggregate 4 nodes per wave, 2 at a time ----
    int slot = lane >> 4, cg = lane & 15;
    int boff = cg * 8;
    #pragma unroll
    for (int p = 0; p < 2; ++p) {
        int n0 = nb + wave * 4 + 2 * p;
        int n1 = n0 + 1;
        int deg0 = cnt[n0]; if (deg0 > CAP) deg0 = CAP;   // wave-uniform scalar loads
        int deg1 = cnt[n1]; if (deg1 > CAP) deg1 = CAP;
        floatx2 a0[4], a1[4];
        #pragma unroll
        for (int j = 0; j < 4; ++j) { a0[j] = (floatx2)(0.f); a1[j] = (floatx2)(0.f); }
        if (slot == 0) {
            uint2 q0 = *(const uint2*)(in + (size_t)n0 * CH + boff);
            uint2 q1 = *(const uint2*)(in + (size_t)n1 * CH + boff);
            acc8(q0, a0); acc8(q1, a1);
        }
        int b0 = n0 * CAP, e0 = b0 + deg0;
        int b1 = n1 * CAP, e1 = b1 + deg1;
        while (b0 + 16 <= e0 && b1 + 16 <= e1) {       // both chains in flight
            round16(in, ssrc, b0, slot, boff, a0);
            round16(in, ssrc, b1, slot, boff, a1);
            b0 += 16; b1 += 16;
        }
        while (b0 + 16 <= e0) { round16(in, ssrc, b0, slot, boff, a0); b0 += 16; }
        while (b1 + 16 <= e1) { round16(in, ssrc, b1, slot, boff, a1); b1 += 16; }
        if (b0 < e0) tail16(in, ssrc, b0, e0, slot, boff, a0);
        if (b1 < e1) tail16(in, ssrc, b1, e1, slot, boff, a1);

        float f0[8], f1[8];
        #pragma unroll
        for (int j = 0; j < 4; ++j) {
            f0[2 * j] = a0[j][0]; f0[2 * j + 1] = a0[j][1];
            f1[2 * j] = a1[j][0]; f1[2 * j + 1] = a1[j][1];
        }
        #pragma unroll
        for (int j = 0; j < 8; ++j) {
            f0[j] += __shfl_xor(f0[j], 16);
            f0[j] += __shfl_xor(f0[j], 32);
            f1[j] += __shfl_xor(f1[j], 16);
            f1[j] += __shfl_xor(f1[j], 32);
        }
        if (slot == 0) {
            short8 o0, o1;
            #pragma unroll
            for (int j = 0; j < 8; ++j) { o0[j] = (short)f2b(f0[j]); o1[j] = (short)f2b(f1[j]); }
            *(short8*)&A[(wave * 4 + 2 * p) * 136 + boff] = o0;
            *(short8*)&A[(wave * 4 + 2 * p + 1) * 136 + boff] = o1;
        }
    }
    __syncthreads();

    // ---- phase B: GEMM1 (A @ WA -> H), 2 col-tiles per wave ----
    short8 af[4];                                      // A[m=l16][k=quad*8+j]
    #pragma unroll
    for (int kc = 0; kc < 4; ++kc)
        af[kc] = *(const short8*)&A[l16 * 136 + kc * 32 + quad * 8];

    #pragma unroll
    for (int half = 0; half < 2; ++half) {
        int ct = wave + half * 4;
        floatx4 a0 = (floatx4)(0.f);
        #pragma unroll
        for (int kc = 0; kc < 4; ++kc) {
            short8 bf = *(const short8*)(wtA + (((ct * 4 + kc) * 4 + quad) * 16 + l16) * 8);
            a0 = __builtin_amdgcn_mfma_f32_16x16x32_bf16(af[kc], bf, a0, 0, 0, 0);
        }
        float bv = biasA[ct * 16 + l16];
        #pragma unroll
        for (int r = 0; r < 4; ++r)                    // C/D: row=quad*4+r, col=l16
            H[(quad * 4 + r) * 136 + ct * 16 + l16] = f2b(fmaxf(a0[r] + bv, 0.f));
    }
    __syncthreads();

    // ---- GEMM2 (H @ WB -> out) ----
    short8 af2[4];
    #pragma unroll
    for (int kc = 0; kc < 4; ++kc)
        af2[kc] = *(const short8*)&H[l16 * 136 + kc * 32 + quad * 8];

    #pragma unroll
    for (int half = 0; half < 2; ++half) {
        int ct = wave + half * 4;
        floatx4 a0 = (floatx4)(0.f);
        #pragma unroll
        for (int kc = 0; kc < 4; ++kc) {
            short8 bf = *(const short8*)(wtB + (((ct * 4 + kc) * 4 + quad) * 16 + l16) * 8);
            a0 = __builtin_amdgcn_mfma_f32_16x16x32_bf16(af2[kc], bf, a0, 0, 0, 0);
        }
        int col = ct * 16 + l16;
        float bv = biasB[col];
        if (DO_POOL) {
            float vr[4];
            #pragma unroll
            for (int r = 0; r < 4; ++r) vr[r] = fmaxf(a0[r] + bv, 0.f);
            for (int g = glo; g <= ghi; ++g) {         // span 1-2 graphs typically
                float s = 0.f;
                #pragma unroll
                for (int r = 0; r < 4; ++r) s += (gg[r] == g) ? vr[r] : 0.f;
                s += __shfl_xor(s, 16);                // reduce across quads
                s += __shfl_xor(s, 32);
                if (lane < 16) atomicAdd(&gsum[g * CH + col], s);
            }
        } else {
            #pragma unroll
            for (int r = 0; r < 4; ++r) {
                int row = nb + quad * 4 + r;
                outq[(size_t)row * CH + col] = f2q(fmaxf(a0[r] + bv, 0.f));
            }
        }
    }
}

// ---- final: out[g] = dot(gsum[g]/count_g, fcw) + fcb ----------------------
__global__ __launch_bounds__(128) void pool_final(const float* __restrict__ gsum, const int* __restrict__ batch,
                                                  const float* __restrict__ fcw, const float* __restrict__ fcb,
                                                  float* __restrict__ outp) {
    int g = blockIdx.x, t = threadIdx.x;
    __shared__ int se[2];
    if (t < 2) {
        int target = g + t, lo = 0, hi = NN;
        while (lo < hi) { int mid = (lo + hi) >> 1; if (batch[mid] < target) lo = mid + 1; else hi = mid; }
        se[t] = lo;
    }
    __syncthreads();
    int cnt = se[1] - se[0]; if (cnt < 1) cnt = 1;
    float v = gsum[g * CH + t] * fcw[t] / (float)cnt;
    __shared__ float red[128];
    red[t] = v; __syncthreads();
    for (int s = 64; s > 0; s >>= 1) { if (t < s) red[t] += red[t + s]; __syncthreads(); }
    if (t == 0) outp[g] = red[0] + fcb[0];
}

extern "C" void kernel_launch(void* const* d_in, const int* in_sizes, int n_in,
                              void* d_out, int out_size, void* d_ws, size_t ws_size,
                              hipStream_t stream) {
    const float* x   = (const float*)d_in[0];
    const int*   ei  = (const int*)d_in[1];
    const int* batch = (const int*)d_in[2];
    const float* W1a = (const float*)d_in[3];
    const float* b1a = (const float*)d_in[4];
    const float* W1b = (const float*)d_in[5];
    const float* b1b = (const float*)d_in[6];
    const float* W2a = (const float*)d_in[7];
    const float* b2a = (const float*)d_in[8];
    const float* W2b = (const float*)d_in[9];
    const float* b2b = (const float*)d_in[10];
    const float* fcw = (const float*)d_in[11];
    const float* fcb = (const float*)d_in[12];
    float* out = (float*)d_out;

    char* w = (char*)d_ws;
    u8*  xq   = (u8*)w;  w += (size_t)NN * CH;       // fp8 x
    u8*  hq   = (u8*)w;  w += (size_t)NN * CH;       // fp8 layer-1 output
    u16* wt   = (u16*)w; w += (size_t)4 * 16384 * 2;
    int* cnt  = (int*)w; w += (size_t)NN * 4;
    float* gsum = (float*)w; w += (size_t)NG * CH * 4;
    int* ssrc = (int*)w; w += (size_t)NN * CAP * 4;  // 7.68MB bins

    hipMemsetAsync(cnt, 0, (size_t)NN * 4, stream);  // ordered before prep's binning

    prep<<<6884, 256, 0, stream>>>(x, xq, W1a, W1b, W2a, W2b, wt, gsum, ei, cnt, ssrc);

    layer<0><<<1250, 256, 0, stream>>>(xq, cnt, ssrc, wt + 0 * 16384, wt + 1 * 16384, b1a, b1b, hq, batch, gsum);
    layer<1><<<1250, 256, 0, stream>>>(hq, cnt, ssrc, wt + 2 * 16384, wt + 3 * 16384, b2a, b2b, hq, batch, gsum);

    pool_final<<<NG, 128, 0, stream>>>(gsum, batch, fcw, fcb, out);
}

// Round 17
// 156.212 us; speedup vs baseline: 1.0445x; 1.0445x over previous
//
#include <hip/hip_runtime.h>

#define NN 20000
#define NE 640000
#define CH 128
#define NG 64
#define NSLICE (NN / 8)
#define CAP 96          // bin capacity; P(Poisson(32) > 96) ~ 1e-18

typedef unsigned short u16;
typedef unsigned char u8;
typedef __attribute__((ext_vector_type(8))) short short8;   // 8 bf16 (4 VGPRs)
typedef __attribute__((ext_vector_type(4))) float floatx4;  // 4 fp32 acc
typedef __attribute__((ext_vector_type(2))) float floatx2;

__device__ __forceinline__ u16 f2b(float f) {
    unsigned int u = __float_as_uint(f);
    u += 0x7fff + ((u >> 16) & 1);          // RNE
    return (u16)(u >> 16);
}
__device__ __forceinline__ u8 f2q(float f) {        // f32 -> fp8 e4m3 (OCP, HW cvt)
    return (u8)(__builtin_amdgcn_cvt_pk_fp8_f32(f, f, 0, false) & 0xff);
}
// accumulate 8 fp8 (uint2) into 4 float2 accs: 4 pk-cvt + 4 pk-add
__device__ __forceinline__ void acc8(uint2 q, floatx2* a) {
    a[0] += __builtin_amdgcn_cvt_pk_f32_fp8(q.x, false);
    a[1] += __builtin_amdgcn_cvt_pk_f32_fp8(q.x, true);
    a[2] += __builtin_amdgcn_cvt_pk_f32_fp8(q.y, false);
    a[3] += __builtin_amdgcn_cvt_pk_f32_fp8(q.y, true);
}
// one 16-edge round: 1 int4 index load + 4 row gathers
__device__ __forceinline__ void round16(const u8* __restrict__ in, const int* __restrict__ ssrc,
                                        int base, int slot, int boff, floatx2* a) {
    int4 si = *(const int4*)&ssrc[base + slot * 4];
    uint2 q0 = *(const uint2*)(in + (size_t)si.x * CH + boff);
    uint2 q1 = *(const uint2*)(in + (size_t)si.y * CH + boff);
    uint2 q2 = *(const uint2*)(in + (size_t)si.z * CH + boff);
    uint2 q3 = *(const uint2*)(in + (size_t)si.w * CH + boff);
    acc8(q0, a); acc8(q1, a); acc8(q2, a); acc8(q3, a);
}
__device__ __forceinline__ void tail16(const u8* __restrict__ in, const int* __restrict__ ssrc,
                                       int base, int e, int slot, int boff, floatx2* a) {
    int i0 = base + slot * 4;
    int4 si = *(const int4*)&ssrc[i0];
    bool ok0 = i0 + 0 < e, ok1 = i0 + 1 < e, ok2 = i0 + 2 < e, ok3 = i0 + 3 < e;
    int s0 = ok0 ? si.x : 0, s1 = ok1 ? si.y : 0, s2 = ok2 ? si.z : 0, s3 = ok3 ? si.w : 0;
    uint2 q0 = *(const uint2*)(in + (size_t)s0 * CH + boff);
    uint2 q1 = *(const uint2*)(in + (size_t)s1 * CH + boff);
    uint2 q2 = *(const uint2*)(in + (size_t)s2 * CH + boff);
    uint2 q3 = *(const uint2*)(in + (size_t)s3 * CH + boff);
    if (!ok0) q0 = make_uint2(0, 0);                   // fp8 0x00 == 0.0
    if (!ok1) q1 = make_uint2(0, 0);
    if (!ok2) q2 = make_uint2(0, 0);
    if (!ok3) q3 = make_uint2(0, 0);
    acc8(q0, a); acc8(q1, a); acc8(q2, a); acc8(q3, a);
}

// ---- prep: x->fp8, weights->bf16 B-frag order, zero gsum, binned CSR ------
__global__ __launch_bounds__(256) void prep(const float* __restrict__ x, u8* __restrict__ xq,
                                            const float* __restrict__ W1a, const float* __restrict__ W1b,
                                            const float* __restrict__ W2a, const float* __restrict__ W2b,
                                            u16* __restrict__ wt, float* __restrict__ gsum,
                                            const int* __restrict__ ei,
                                            int* __restrict__ cnt, int* __restrict__ ssrc) {
    int b = blockIdx.x;
    if (b < 2500) {                                   // x: 2.56M elems, 4/thread -> fp8
        int idx = (b * 256 + threadIdx.x) * 4;
        float4 v = *(const float4*)(x + idx);
        int pk = __builtin_amdgcn_cvt_pk_fp8_f32(v.x, v.y, 0, false);
        pk = __builtin_amdgcn_cvt_pk_fp8_f32(v.z, v.w, pk, true);
        *(unsigned int*)(xq + idx) = (unsigned int)pk;
    } else if (b < 2756) {                            // weights: 4 x 16384 elems (bf16 frags)
        int wi = b - 2500;                            // 0..255
        int m = wi >> 6;
        int r = (wi & 63) * 256 + threadIdx.x;        // 0..16383
        int j = r & 7, l16 = (r >> 3) & 15, quad = (r >> 7) & 3;
        int kc = (r >> 9) & 3, ct = (r >> 11) & 7;
        int n = ct * 16 + l16, k = kc * 32 + quad * 8 + j;
        const float* W = (m == 0) ? W1a : (m == 1) ? W1b : (m == 2) ? W2a : W2b;
        wt[m * 16384 + r] = f2b(W[k * 128 + n]);
    } else if (b < 2788) {                            // zero gsum (8192 floats)
        gsum[(b - 2756) * 256 + threadIdx.x] = 0.f;
    } else {                                          // binned CSR: 4096 blocks
        int idx = b - 2788;
        int slice = idx & 7, chunk = idx >> 3;        // 512 chunks x 1250 edges
        int lo = slice * NSLICE, hi = lo + NSLICE;
        int e0 = chunk * 1250, e1 = e0 + 1250;
        for (int e = e0 + threadIdx.x; e < e1; e += 256) {
            int dst = ei[NE + e];
            if (dst >= lo && dst < hi) {
                int pos = atomicAdd(&cnt[dst], 1);
                if (pos < CAP) ssrc[dst * CAP + pos] = ei[e];
            }
        }
    }
}

// ---- fused layer: aggregate (fp8 gather) + MLP, 16 nodes/block ------------
// 512 thr = 8 waves (2x the waves/CU of the 256-thr version -> 2x latency
// hiding for phase A). Each wave aggregates 2 nodes, both chains in flight.
// Phase B: GEMM1/GEMM2, 8 col-tiles, 1 per wave, H in LDS.
// DO_POOL: in-register masked reduce + global atomics to L2-resident gsum.
template <int DO_POOL>
__global__ __launch_bounds__(512) void layer(const u8* __restrict__ in,
                                             const int* __restrict__ cnt, const int* __restrict__ ssrc,
                                             const u16* __restrict__ wtA, const u16* __restrict__ wtB,
                                             const float* __restrict__ biasA, const float* __restrict__ biasB,
                                             u8* __restrict__ outq,
                                             const int* __restrict__ batch, float* __restrict__ gsum) {
    __shared__ u16 A[16 * 136];
    __shared__ u16 H[16 * 136];
    int t = threadIdx.x, wave = t >> 6, lane = t & 63;
    int quad = lane >> 4, l16 = lane & 15;
    int nb = blockIdx.x * 16;                          // 1250*16 = 20000 exact

    int gg[4], glo = 0, ghi = 0;
    if (DO_POOL) {
        glo = batch[nb]; ghi = batch[nb + 15];
        #pragma unroll
        for (int r = 0; r < 4; ++r)
            gg[r] = batch[nb + quad * 4 + r];
    }

    // ---- phase A: each wave aggregates 2 nodes, interleaved ----
    int slot = lane >> 4, cg = lane & 15;
    int boff = cg * 8;
    {
        int n0 = nb + 2 * wave;
        int n1 = n0 + 1;
        int deg0 = cnt[n0]; if (deg0 > CAP) deg0 = CAP;   // wave-uniform scalar loads
        int deg1 = cnt[n1]; if (deg1 > CAP) deg1 = CAP;
        floatx2 a0[4], a1[4];
        #pragma unroll
        for (int j = 0; j < 4; ++j) { a0[j] = (floatx2)(0.f); a1[j] = (floatx2)(0.f); }
        if (slot == 0) {
            uint2 q0 = *(const uint2*)(in + (size_t)n0 * CH + boff);
            uint2 q1 = *(const uint2*)(in + (size_t)n1 * CH + boff);
            acc8(q0, a0); acc8(q1, a1);
        }
        int b0 = n0 * CAP, e0 = b0 + deg0;
        int b1 = n1 * CAP, e1 = b1 + deg1;
        while (b0 + 16 <= e0 && b1 + 16 <= e1) {       // both chains in flight
            round16(in, ssrc, b0, slot, boff, a0);
            round16(in, ssrc, b1, slot, boff, a1);
            b0 += 16; b1 += 16;
        }
        while (b0 + 16 <= e0) { round16(in, ssrc, b0, slot, boff, a0); b0 += 16; }
        while (b1 + 16 <= e1) { round16(in, ssrc, b1, slot, boff, a1); b1 += 16; }
        if (b0 < e0) tail16(in, ssrc, b0, e0, slot, boff, a0);
        if (b1 < e1) tail16(in, ssrc, b1, e1, slot, boff, a1);

        float f0[8], f1[8];
        #pragma unroll
        for (int j = 0; j < 4; ++j) {
            f0[2 * j] = a0[j][0]; f0[2 * j + 1] = a0[j][1];
            f1[2 * j] = a1[j][0]; f1[2 * j + 1] = a1[j][1];
        }
        #pragma unroll
        for (int j = 0; j < 8; ++j) {
            f0[j] += __shfl_xor(f0[j], 16);
            f0[j] += __shfl_xor(f0[j], 32);
            f1[j] += __shfl_xor(f1[j], 16);
            f1[j] += __shfl_xor(f1[j], 32);
        }
        if (slot == 0) {
            short8 o0, o1;
            #pragma unroll
            for (int j = 0; j < 8; ++j) { o0[j] = (short)f2b(f0[j]); o1[j] = (short)f2b(f1[j]); }
            *(short8*)&A[(2 * wave) * 136 + boff] = o0;
            *(short8*)&A[(2 * wave + 1) * 136 + boff] = o1;
        }
    }
    __syncthreads();

    // ---- phase B: GEMM1 (A @ WA -> H), 1 col-tile per wave ----
    short8 af[4];                                      // A[m=l16][k=quad*8+j]
    #pragma unroll
    for (int kc = 0; kc < 4; ++kc)
        af[kc] = *(const short8*)&A[l16 * 136 + kc * 32 + quad * 8];

    {
        int ct = wave;
        floatx4 a0 = (floatx4)(0.f);
        #pragma unroll
        for (int kc = 0; kc < 4; ++kc) {
            short8 bf = *(const short8*)(wtA + (((ct * 4 + kc) * 4 + quad) * 16 + l16) * 8);
            a0 = __builtin_amdgcn_mfma_f32_16x16x32_bf16(af[kc], bf, a0, 0, 0, 0);
        }
        float bv = biasA[ct * 16 + l16];
        #pragma unroll
        for (int r = 0; r < 4; ++r)                    // C/D: row=quad*4+r, col=l16
            H[(quad * 4 + r) * 136 + ct * 16 + l16] = f2b(fmaxf(a0[r] + bv, 0.f));
    }
    __syncthreads();

    // ---- GEMM2 (H @ WB -> out) ----
    short8 af2[4];
    #pragma unroll
    for (int kc = 0; kc < 4; ++kc)
        af2[kc] = *(const short8*)&H[l16 * 136 + kc * 32 + quad * 8];

    {
        int ct = wave;
        floatx4 a0 = (floatx4)(0.f);
        #pragma unroll
        for (int kc = 0; kc < 4; ++kc) {
            short8 bf = *(const short8*)(wtB + (((ct * 4 + kc) * 4 + quad) * 16 + l16) * 8);
            a0 = __builtin_amdgcn_mfma_f32_16x16x32_bf16(af2[kc], bf, a0, 0, 0, 0);
        }
        int col = ct * 16 + l16;
        float bv = biasB[col];
        if (DO_POOL) {
            float vr[4];
            #pragma unroll
            for (int r = 0; r < 4; ++r) vr[r] = fmaxf(a0[r] + bv, 0.f);
            for (int g = glo; g <= ghi; ++g) {         // span 1-2 graphs typically
                float s = 0.f;
                #pragma unroll
                for (int r = 0; r < 4; ++r) s += (gg[r] == g) ? vr[r] : 0.f;
                s += __shfl_xor(s, 16);                // reduce across quads
                s += __shfl_xor(s, 32);
                if (lane < 16) atomicAdd(&gsum[g * CH + col], s);
            }
        } else {
            #pragma unroll
            for (int r = 0; r < 4; ++r) {
                int row = nb + quad * 4 + r;
                outq[(size_t)row * CH + col] = f2q(fmaxf(a0[r] + bv, 0.f));
            }
        }
    }
}

// ---- final: out[g] = dot(gsum[g]/count_g, fcw) + fcb ----------------------
__global__ __launch_bounds__(128) void pool_final(const float* __restrict__ gsum, const int* __restrict__ batch,
                                                  const float* __restrict__ fcw, const float* __restrict__ fcb,
                                                  float* __restrict__ outp) {
    int g = blockIdx.x, t = threadIdx.x;
    __shared__ int se[2];
    if (t < 2) {
        int target = g + t, lo = 0, hi = NN;
        while (lo < hi) { int mid = (lo + hi) >> 1; if (batch[mid] < target) lo = mid + 1; else hi = mid; }
        se[t] = lo;
    }
    __syncthreads();
    int cnt = se[1] - se[0]; if (cnt < 1) cnt = 1;
    float v = gsum[g * CH + t] * fcw[t] / (float)cnt;
    __shared__ float red[128];
    red[t] = v; __syncthreads();
    for (int s = 64; s > 0; s >>= 1) { if (t < s) red[t] += red[t + s]; __syncthreads(); }
    if (t == 0) outp[g] = red[0] + fcb[0];
}

extern "C" void kernel_launch(void* const* d_in, const int* in_sizes, int n_in,
                              void* d_out, int out_size, void* d_ws, size_t ws_size,
                              hipStream_t stream) {
    const float* x   = (const float*)d_in[0];
    const int*   ei  = (const int*)d_in[1];
    const int* batch = (const int*)d_in[2];
    const float* W1a = (const float*)d_in[3];
    const float* b1a = (const float*)d_in[4];
    const float* W1b = (const float*)d_in[5];
    const float* b1b = (const float*)d_in[6];
    const float* W2a = (const float*)d_in[7];
    const float* b2a = (const float*)d_in[8];
    const float* W2b = (const float*)d_in[9];
    const float* b2b = (const float*)d_in[10];
    const float* fcw = (const float*)d_in[11];
    const float* fcb = (const float*)d_in[12];
    float* out = (float*)d_out;

    char* w = (char*)d_ws;
    u8*  xq   = (u8*)w;  w += (size_t)NN * CH;       // fp8 x
    u8*  hq   = (u8*)w;  w += (size_t)NN * CH;       // fp8 layer-1 output
    u16* wt   = (u16*)w; w += (size_t)4 * 16384 * 2;
    int* cnt  = (int*)w; w += (size_t)NN * 4;
    float* gsum = (float*)w; w += (size_t)NG * CH * 4;
    int* ssrc = (int*)w; w += (size_t)NN * CAP * 4;  // 7.68MB bins

    hipMemsetAsync(cnt, 0, (size_t)NN * 4, stream);  // ordered before prep's binning

    prep<<<6884, 256, 0, stream>>>(x, xq, W1a, W1b, W2a, W2b, wt, gsum, ei, cnt, ssrc);

    layer<0><<<1250, 512, 0, stream>>>(xq, cnt, ssrc, wt + 0 * 16384, wt + 1 * 16384, b1a, b1b, hq, batch, gsum);
    layer<1><<<1250, 512, 0, stream>>>(hq, cnt, ssrc, wt + 2 * 16384, wt + 3 * 16384, b2a, b2b, hq, batch, gsum);

    pool_final<<<NG, 128, 0, stream>>>(gsum, batch, fcw, fcb, out);
}